// Round 1
// baseline (365.668 us; speedup 1.0000x reference)
//
#include <hip/hip_runtime.h>

// LIF neuron layer forward (fp32):
//   v_t = BETA * v_{t-1} * (1 - s_{t-1}) + i_t   (hard reset)
//   s_t = (v_t >= 1.0) ? 1 : 0
// Outputs flat-concat: spikes (B,T,H), membrane (B,T,H), v_final (B,H)
// B=16, T=1024, H=2048.  Memory-bound: ~403 MB -> ~64 us @ 6.3 TB/s.
//
// R4 theory: R3's per-chunk __syncthreads drained vmcnt(0) every chunk,
// forcing a full NT-store round-trip on the critical path 32x, and 1 wave/CU
// gave zero TLP. This version:
//   * 1 float per lane -> 512 blocks (2 waves/CU, 2x TLP).
//   * NO __syncthreads (block == 1 wave): counted s_waitcnt vmcnt(N) only.
//     Stores are never drained in the loop; staging runs 3 chunks ahead.
//   * vmcnt accounting (in-issue-order retirement): per chunk we issue
//     32 stores + 4 global_load_lds. Steady-state fence vmcnt(40) leaves
//     {stage(c+2):4, stores(c):32, stage(c+3):4} in flight and guarantees
//     stage(c+1) has landed. Unknown compiler vmem ops only make the fence
//     stricter (safe).

constexpr int B_  = 16;
constexpr int T_  = 1024;
constexpr int H_  = 2048;
constexpr float BETA = 0.904837f;

constexpr int C   = 16;          // time-steps per chunk
constexpr int NCH = T_ / C;      // 64 chunks
constexpr int OPS = (C * 64) / (64 * 4);  // 4 staging ops per chunk (16B/lane)

__device__ __forceinline__ void async_copy16(const void* g, void* s) {
    // global -> LDS direct copy, 16 B per lane. LDS dest = uniform base + lane*16.
    __builtin_amdgcn_global_load_lds(
        (const __attribute__((address_space(1))) void*)g,
        (__attribute__((address_space(3))) void*)s,
        16, 0, 0);
}

__global__ __launch_bounds__(64) void lif_fwd_kernel(
    const float* __restrict__ in,   // (B,T,H)
    const float* __restrict__ v0,   // (B,H)
    float* __restrict__ sp,         // (B,T,H)
    float* __restrict__ mem,        // (B,T,H)
    float* __restrict__ vf)         // (B,H)
{
    __shared__ float lds_buf[4][C * 64];   // 4 x 4 KB

    const int lane = threadIdx.x;          // 0..63
    const int w    = blockIdx.x;           // 0..511 (one wave per block)
    const int b    = w >> 5;               // batch row (32 col-blocks per batch)
    const int col  = (w & 31) * 64;        // float column base of this wave

    const size_t seq = (size_t)b * T_ * H_ + col;   // float units

    // Staging source: one op covers 4 time-rows x 256 B.
    // lane l -> row (l>>4), bytes (l&15)*16.  LDS lands row-major [step][64 floats].
    const char* sbase = (const char*)(in + seq)
                      + (size_t)(lane >> 4) * (H_ * 4)
                      + (size_t)(lane & 15) * 16;

    float* __restrict__ spp = sp  + seq + lane;
    float* __restrict__ mpp = mem + seq + lane;

    const int vidx = b * H_ + col + lane;
    float v = v0[vidx];
    float s = 0.0f;

    auto stage = [&](int c) {
        const char* gb = sbase + (size_t)c * C * (H_ * 4);
#pragma unroll
        for (int p = 0; p < OPS; ++p)
            async_copy16(gb + (size_t)(4 * p) * (H_ * 4),
                         &lds_buf[c & 3][p * 256]);
    };

    // Prologue: stage chunks 0..2 (12 ops). Fence to 8 outstanding ->
    // retires (v0 load +) stage(0); stage(1),stage(2) stay in flight.
    stage(0); stage(1); stage(2);
    asm volatile("s_waitcnt vmcnt(8)" ::: "memory");

    for (int c = 0; c < NCH; ++c) {
        const float* lbuf = lds_buf[c & 3];
        const size_t obase = (size_t)c * C * H_;
#pragma unroll
        for (int t = 0; t < C; ++t) {
            const float x = lbuf[t * 64 + lane];

            // s in {0,1}: (1-s) multiply is exact -> FMA contraction is
            // bit-identical to the two-step reference.
            v = BETA * v * (1.0f - s) + x;
            s = (v >= 1.0f) ? 1.0f : 0.0f;

            const size_t o = obase + (size_t)t * H_;
            __builtin_nontemporal_store(s, spp + o);
            __builtin_nontemporal_store(v, mpp + o);
        }

        if (c + 3 < NCH) stage(c + 3);

        // Counted fence: guarantee stage(c+1) landed before next iteration's
        // ds_reads, while leaving the newest stores + 2 staged chunks in
        // flight. In-order vmcnt retirement makes these counts exact:
        //   steady: younger-than-stage(c+1) kept = stage(c+2)4 + stores(c)32
        //           + stage(c+3)4 = 40
        //   tails drop the missing stage ops.
        if (c + 3 < NCH)       asm volatile("s_waitcnt vmcnt(40)" ::: "memory");
        else if (c + 2 < NCH)  asm volatile("s_waitcnt vmcnt(36)" ::: "memory");
        else if (c + 1 < NCH)  asm volatile("s_waitcnt vmcnt(32)" ::: "memory");
    }

    vf[vidx] = v;
}

extern "C" void kernel_launch(void* const* d_in, const int* in_sizes, int n_in,
                              void* d_out, int out_size, void* d_ws, size_t ws_size,
                              hipStream_t stream) {
    const float* in = (const float*)d_in[0];   // (B,T,H)
    const float* v0 = (const float*)d_in[1];   // (B,H)

    float* out = (float*)d_out;
    const size_t n_bth = (size_t)B_ * T_ * H_;
    float* sp  = out;                          // spikes
    float* mem = out + n_bth;                  // membrane
    float* vf  = out + 2 * n_bth;              // v_final

    const int grid = B_ * (H_ / 64);           // 512 blocks, 1 wave each
    lif_fwd_kernel<<<grid, 64, 0, stream>>>(in, v0, sp, mem, vf);
}